// Round 13
// baseline (47.846 us; speedup 1.0000x reference)
//
#include <hip/hip_runtime.h>

#define NB 16
#define NC 8
#define HW (512*512)
#define NT 16                 // tags 1..16 (tag 0 never participates)
#define LGG 3.0f

#define BLOCKS 512            // 2 blocks/CU (LDS-bound), all co-resident
#define THREADS 512           // 8 waves -> 16 waves/CU total
#define WPB 8
#define BPSAMP (BLOCKS/NB)    // 32 blocks per sample
#define PXB (HW/BPSAMP)       // 8192 pixels per block
#define TILE 1024             // pixels per staged tile
#define NTILES (PXB/TILE)     // 8
#define JITERS 4              // 128 px per wave per j-iter
#define NCOL 10               // D cols: 0..7 ch sums, 8 count, 9 masked count
#define ACCW (NT*NCOL)        // 160 floats per slice

// double-buffered tile: [GK 4KB][MASK 4KB][SIM 8x4KB] = 40960 B per buffer
#define GK_OFF  0
#define MK_OFF  4096
#define SIM_OFF 8192
#define BUF_BYTES 40960
#define LDS_BYTES (2*BUF_BYTES)     // 81920 -> exactly 2 blocks/CU

typedef __attribute__((ext_vector_type(8))) short bf16x8;
typedef __attribute__((ext_vector_type(4))) float f32x4;

__device__ __forceinline__ unsigned pk_bf16(float x, float y) {
    unsigned r;
    asm("v_cvt_pk_bf16_f32 %0, %1, %2" : "=v"(r) : "v"(x), "v"(y));
    return r;   // lo = bf16(x), hi = bf16(y), RNE
}
__device__ __forceinline__ unsigned onehot2(int a, int b, int r1) {
    return (a == r1 ? 0x3F80u : 0u) | (b == r1 ? 0x3F800000u : 0u);
}
__device__ __forceinline__ unsigned mask2(int a, int b) {
    return (a ? 0x3F80u : 0u) | (b ? 0x3F800000u : 0u);
}
__device__ __forceinline__ void gload_lds16(const void* g, void* lds) {
    __builtin_amdgcn_global_load_lds(
        (const __attribute__((address_space(1))) void*)g,
        (__attribute__((address_space(3))) void*)lds, 16, 0, 0);
}

// stage one 1024-px tile: 40 x 1KB chunks, wave w takes idx = w, w+8, ... (5 each).
// sim plane p rotated by 16*p bytes within its 4KB (pre-swizzled GLOBAL src,
// linear LDS dest) to spread the plane-stride bank pattern.
__device__ __forceinline__ void stage(const char* gkB, const char* mkB,
                                      const char* smB, char* buf,
                                      int t0b, int wid, int lane) {
    #pragma unroll
    for (int k = 0; k < 5; ++k) {
        const int idx = wid + 8 * k;
        const char* src; int dst;
        if (idx < 4) {
            src = gkB + t0b + idx * 1024 + lane * 16;
            dst = GK_OFF + idx * 1024 + lane * 16;
        } else if (idx < 8) {
            src = mkB + t0b + (idx - 4) * 1024 + lane * 16;
            dst = MK_OFF + (idx - 4) * 1024 + lane * 16;
        } else {
            const int s = idx - 8, p = s >> 2, h = s & 3;
            const int local = h * 1024 + lane * 16;
            const int goff = (local - 16 * p) & 4095;     // inverse rotation
            src = smB + (size_t)p * (HW * 4) + t0b + goff;
            dst = SIM_OFF + p * 4096 + local;
        }
        gload_lds16(src, buf + dst);
    }
}

__global__ __launch_bounds__(THREADS) void accum(
    const int* __restrict__ gk, const int* __restrict__ mask,
    const float* __restrict__ sim, float* __restrict__ psum)
{
    const int tid  = threadIdx.x;
    const int lane = tid & 63, wid = tid >> 6;
    const int bid  = blockIdx.x;
    const int b    = bid / BPSAMP;          // sample
    const int sb   = bid % BPSAMP;          // block within sample
    const int c    = lane & 15;             // D column role: 0..7 ch, 8 ones, 9 mask
    const int l4   = lane >> 4;             // k-chunk 0..3 (8 px each)
    const int base = sb * PXB;

    __shared__ __align__(16) char lds[LDS_BYTES];

    const char* gkB = (const char*)(gk   + (size_t)b * HW + base);
    const char* mkB = (const char*)(mask + (size_t)b * HW + base);
    const char* smB = (const char*)(sim  + (size_t)b * NC * HW + base);

    f32x4 acc = {0.f, 0.f, 0.f, 0.f};
    const int r1 = c + 1;
    const int pl = c & 7;                   // sim plane (c<8 lanes)
    const int rot = 16 * pl;

    stage(gkB, mkB, smB, lds, 0, wid, lane);            // tile 0 -> buf 0

    #pragma unroll 1
    for (int t = 0; t < NTILES; ++t) {
        char* cur = lds + (t & 1) * BUF_BYTES;
        if (t + 1 < NTILES) {
            stage(gkB, mkB, smB, lds + ((t + 1) & 1) * BUF_BYTES,
                  (t + 1) * (TILE * 4), wid, lane);
            asm volatile("s_waitcnt vmcnt(5)" ::: "memory");  // tile t drained;
        } else {                                              // t+1's 5 in flight
            asm volatile("s_waitcnt vmcnt(0)" ::: "memory");
        }
        __builtin_amdgcn_sched_barrier(0);
        __builtin_amdgcn_s_barrier();       // all waves' tile-t chunks visible

        #pragma unroll
        for (int j = 0; j < JITERS; ++j) {
            const int o = (wid * 128 + j * 32 + l4 * 8) * 4;  // byte off, <4096
            const int4 g0 = *(const int4*)(cur + GK_OFF + o);
            const int4 g1 = *(const int4*)(cur + GK_OFF + o + 16);
            float4 v0 = {0,0,0,0}, v1 = {0,0,0,0};
            if (c < 8) {
                const char* sp = cur + SIM_OFF + pl * 4096;
                v0 = *(const float4*)(sp + ((o + rot) & 4095));
                v1 = *(const float4*)(sp + ((o + 16 + rot) & 4095));
            }
            int4 m0 = {0,0,0,0}, m1 = {0,0,0,0};
            if (c == 9) {
                m0 = *(const int4*)(cur + MK_OFF + o);
                m1 = *(const int4*)(cur + MK_OFF + o + 16);
            }

            union { bf16x8 v; unsigned u[4]; } A, B;
            A.u[0] = onehot2(g0.x, g0.y, r1);
            A.u[1] = onehot2(g0.z, g0.w, r1);
            A.u[2] = onehot2(g1.x, g1.y, r1);
            A.u[3] = onehot2(g1.z, g1.w, r1);
            const unsigned bs0 = pk_bf16(v0.x, v0.y), bs1 = pk_bf16(v0.z, v0.w);
            const unsigned bs2 = pk_bf16(v1.x, v1.y), bs3 = pk_bf16(v1.z, v1.w);
            const unsigned bm0 = mask2(m0.x, m0.y), bm1 = mask2(m0.z, m0.w);
            const unsigned bm2 = mask2(m1.x, m1.y), bm3 = mask2(m1.z, m1.w);
            B.u[0] = c < 8 ? bs0 : (c == 8 ? 0x3F803F80u : (c == 9 ? bm0 : 0u));
            B.u[1] = c < 8 ? bs1 : (c == 8 ? 0x3F803F80u : (c == 9 ? bm1 : 0u));
            B.u[2] = c < 8 ? bs2 : (c == 8 ? 0x3F803F80u : (c == 9 ? bm2 : 0u));
            B.u[3] = c < 8 ? bs3 : (c == 8 ? 0x3F803F80u : (c == 9 ? bm3 : 0u));

            acc = __builtin_amdgcn_mfma_f32_16x16x32_bf16(A.v, B.v, acc, 0, 0, 0);
        }
        __builtin_amdgcn_s_barrier();       // reads done before parity overwrite
    }

    // ---- tail: block-reduce into a PRIVATE slice (no atomics, no init) ----
    float* lred = (float*)lds;              // overlay, post-barrier safe
    const int row0 = l4 * 4;                // D: col = lane&15, row = l4*4 + reg
    #pragma unroll
    for (int i = 0; i < 4; ++i) lred[wid * 256 + (row0 + i) * 16 + c] = acc[i];
    __syncthreads();

    if (tid < ACCW) {                       // 160: r = tag row, cc = column
        const int r = tid / NCOL, cc = tid % NCOL;
        float s = 0.f;
        #pragma unroll
        for (int w = 0; w < WPB; ++w) s += lred[w * 256 + r * 16 + cc];
        psum[(size_t)bid * ACCW + tid] = s;
    }
}

// one block, 1024 threads: wave w fully handles sample w.
__global__ __launch_bounds__(1024) void finalize(
    const float* __restrict__ psum, float* __restrict__ out)
{
    __shared__ float Sw[NB][ACCW];          // per-sample reduced S
    __shared__ float means_s[NB][NT][NC];
    __shared__ float sl[NB], sn[NB];
    const int tid = threadIdx.x;
    const int w = tid >> 6, lane = tid & 63;   // w = sample

    // reduce 32 slices (coalesced: lane f, f+64, f+128)
    {
        const float* base = psum + (size_t)w * BPSAMP * ACCW;
        float a0 = 0.f, a1 = 0.f, a2 = 0.f;
        #pragma unroll 4
        for (int s = 0; s < BPSAMP; ++s) {
            a0 += base[s * ACCW + lane];
            a1 += base[s * ACCW + lane + 64];
            if (lane < 32) a2 += base[s * ACCW + lane + 128];
        }
        Sw[w][lane] = a0; Sw[w][lane + 64] = a1;
        if (lane < 32) Sw[w][lane + 128] = a2;
    }
    // same-wave LDS write->read: in-order within a wave, compiler inserts waits

    // means (128 (t,c) combos per sample: lane handles idx = lane, lane+64)
    #pragma unroll
    for (int k = 0; k < 2; ++k) {
        const int idx = lane + 64 * k;
        const int t = idx >> 3, cc = idx & 7;
        means_s[w][t][cc] = Sw[w][t * NCOL + cc]
                            / fmaxf(Sw[w][t * NCOL + 8], 1.f);
    }
    // presence: tag t present iff masked count > 0.5 (bit t of ballot)
    const unsigned long long bal =
        __ballot(lane < NT && (Sw[w][lane * NCOL + 9] > 0.5f));
    const unsigned pres = (unsigned)(bal & 0xFFFFull);

    float loss = 0.f, nv = 0.f;
    #pragma unroll
    for (int k = 0; k < 4; ++k) {           // 256 pairs / 64 lanes
        const int pid = lane + 64 * k;
        const int i = pid >> 4, j = pid & 15;
        if (i != j && ((pres >> i) & 1u) && ((pres >> j) & 1u)) {
            float d2 = 0.f;
            #pragma unroll
            for (int cc = 0; cc < NC; ++cc) {
                const float d = means_s[w][i][cc] - means_s[w][j][cc];
                d2 += d * d;
            }
            const float dist = sqrtf(d2 + 1e-12f);
            const float r = fmaxf(LGG - dist, 0.f);
            loss += logf(r * r + 1.f);
            nv += 1.f;
        }
    }
    #pragma unroll
    for (int o = 32; o; o >>= 1) { loss += __shfl_xor(loss, o); nv += __shfl_xor(nv, o); }
    if (lane == 0) {
        const float v = (__popc(pres) >= 2) ? 1.f : 0.f;
        sl[w] = v * (loss / fmaxf(nv, 1.f));
        sn[w] = v;
    }
    __syncthreads();
    if (tid < 64) {
        float l = (tid < NB) ? sl[tid] : 0.f;
        float v = (tid < NB) ? sn[tid] : 0.f;
        #pragma unroll
        for (int o = 8; o; o >>= 1) { l += __shfl_xor(l, o); v += __shfl_xor(v, o); }
        if (tid == 0) out[0] = (v > 0.f) ? l / v : 0.f;
    }
}

extern "C" void kernel_launch(void* const* d_in, const int* in_sizes, int n_in,
                              void* d_out, int out_size, void* d_ws, size_t ws_size,
                              hipStream_t stream) {
    const int*   gk   = (const int*)d_in[0];
    const int*   mask = (const int*)d_in[1];
    const float* sim  = (const float*)d_in[2];
    float* out  = (float*)d_out;
    float* psum = (float*)d_ws;       // BLOCKS*160 floats, fully overwritten

    accum<<<BLOCKS, THREADS, 0, stream>>>(gk, mask, sim, psum);
    finalize<<<1, 1024, 0, stream>>>(psum, out);
}